// Round 3
// baseline (372.162 us; speedup 1.0000x reference)
//
#include <hip/hip_runtime.h>
#include <hip/hip_bf16.h>

typedef __attribute__((ext_vector_type(8))) short short8;
typedef __attribute__((ext_vector_type(4))) float float4v;

#define CAP 48      // per-node edge slots; deg ~ Poisson(16), P(>48) ~ 1e-11
#define OVFCAP 65536

__device__ __forceinline__ unsigned short f2bf(float f) {
    union { float f; unsigned u; } v; v.f = f;
    unsigned r = v.u + 0x7fffu + ((v.u >> 16) & 1u);   // round-to-nearest-even
    return (unsigned short)(r >> 16);
}
__device__ __forceinline__ float bf2f(unsigned short u) {
    union { unsigned u; float f; } v; v.u = ((unsigned)u) << 16; return v.f;
}

// ---------------- K1: fused [edge-build | LN+ReLU | W-prep] -------------
// blockIdx < EB:                 edge adjacency build, 4 edges/thread (ILP atomics)
// EB <= blockIdx < EB+LNB:       LayerNorm+ReLU -> packed bf16 h (wave/row)
// blockIdx >= EB+LNB (16 blks):  pack W fragments (MFMA B layout)
__global__ __launch_bounds__(256) void fused_pre_kernel(
    const float* __restrict__ x, const float* __restrict__ gamma,
    const float* __restrict__ beta, unsigned* __restrict__ hbuf,
    const int* __restrict__ idx, int* __restrict__ deg,
    int* __restrict__ elist, int* __restrict__ novf_ctr,
    int* __restrict__ ovf,
    const float* __restrict__ Wl, const float* __restrict__ Wr,
    unsigned short* __restrict__ wsb,
    int N, int E, int EB, int LNB) {
    const int b = blockIdx.x;
    if (b < EB) {
        // ---- edge build: thread handles 4 consecutive edges
        const int t4 = b * 256 + threadIdx.x;
        const int e0 = t4 * 4;
        if (e0 + 3 >= E) {      // tail (E%4==0 so threads are all-or-nothing)
            return;
        }
        const int4 s = *(const int4*)&idx[e0];
        const int4 d = *(const int4*)&idx[E + e0];
        // 4 independent atomics in flight before any dependent use
        const int p0 = atomicAdd(&deg[d.x], 1);
        const int p1 = atomicAdd(&deg[d.y], 1);
        const int p2 = atomicAdd(&deg[d.z], 1);
        const int p3 = atomicAdd(&deg[d.w], 1);
        int ss[4] = {s.x, s.y, s.z, s.w};
        int dd[4] = {d.x, d.y, d.z, d.w};
        int pp[4] = {p0, p1, p2, p3};
        #pragma unroll
        for (int i = 0; i < 4; i++) {
            if (pp[i] < CAP) {
                elist[(size_t)dd[i] * CAP + pp[i]] = ss[i];
            } else {
                const int op = atomicAdd(novf_ctr, 1);
                if (op < OVFCAP) { ovf[2 * op] = dd[i]; ovf[2 * op + 1] = ss[i]; }
            }
        }
    } else if (b < EB + LNB) {
        // ---- LayerNorm + ReLU
        const int row = (b - EB) * 4 + (threadIdx.x >> 6);
        if (row >= N) return;
        const int lane = threadIdx.x & 63;
        const size_t base = (size_t)row * 128 + lane * 2;
        float2 v = *(const float2*)&x[base];
        float sm = v.x + v.y;
        #pragma unroll
        for (int o = 32; o; o >>= 1) sm += __shfl_xor(sm, o, 64);
        const float mu = sm * 0.0078125f;
        const float d0 = v.x - mu, d1 = v.y - mu;
        float sq = d0 * d0 + d1 * d1;
        #pragma unroll
        for (int o = 32; o; o >>= 1) sq += __shfl_xor(sq, o, 64);
        const float rs = rsqrtf(sq * 0.0078125f + 1e-5f);
        float2 g = *(const float2*)&gamma[lane * 2];
        float2 bb = *(const float2*)&beta[lane * 2];
        float h0 = fmaxf(fmaf(d0 * rs, g.x, bb.x), 0.f);
        float h1 = fmaxf(fmaf(d1 * rs, g.y, bb.y), 0.f);
        hbuf[(size_t)row * 64 + lane] =
            (unsigned)f2bf(h0) | ((unsigned)f2bf(h1) << 16);
    } else {
        // ---- W fragment pack: Wc[n][k] = k<128 ? Wl[n][k] : Wr[n][k-128]
        const int sidx = (b - EB - LNB) * 256 + threadIdx.x;   // 0..4095
        const int tc = sidx >> 9, c = (sidx >> 6) & 7, l = sidx & 63;
        const int n  = tc * 16 + (l & 15);
        const int k0 = c * 32 + ((l >> 4) & 3) * 8;
        const float* w = (k0 < 128) ? (Wl + (size_t)n * 128 + k0)
                                    : (Wr + (size_t)n * 128 + (k0 - 128));
        unsigned short tmp[8];
        #pragma unroll
        for (int j = 0; j < 8; j++) tmp[j] = f2bf(w[j]);
        *(short8*)&wsb[(size_t)sidx * 8] = *(short8*)tmp;
    }
}

// ---------------- K2: gather-reduce + mean + MFMA GEMM + bias + residual
// out[i][:] = mean_j h[j] @ W_l^T + b_l + h[i] @ W_r^T + x[i]
__global__ __launch_bounds__(256) void fused_out_kernel(
    float* __restrict__ out, const int* __restrict__ deg,
    const unsigned* __restrict__ hbuf, const float* __restrict__ x,
    const unsigned short* __restrict__ wsb, const float* __restrict__ bl,
    const int* __restrict__ elist, const int* __restrict__ novf_ctr,
    const int* __restrict__ ovf) {
    __shared__ float smem_agg[16][128];                 // 8 KB
    __shared__ unsigned short a_lds[8][64][8];          // 8 KB
    const int t = threadIdx.x, w = t >> 6, l = t & 63;
    const int row0 = blockIdx.x * 16;

    // ---- Phase 1: wave w gathers+reduces rows w*4 .. w*4+3
    #pragma unroll
    for (int i = 0; i < 4; i++) {
        const int lr = w * 4 + i;
        const int row = row0 + lr;
        const int dv = deg[row];
        const int dcl = dv < CAP ? dv : CAP;
        const int* ep = elist + (size_t)row * CAP;
        float a0 = 0.f, a1 = 0.f;
        int j = 0;
        for (; j + 4 <= dcl; j += 4) {
            int4 s4 = *(const int4*)(ep + j);
            unsigned p0 = hbuf[(size_t)s4.x * 64 + l];
            unsigned p1 = hbuf[(size_t)s4.y * 64 + l];
            unsigned p2 = hbuf[(size_t)s4.z * 64 + l];
            unsigned p3 = hbuf[(size_t)s4.w * 64 + l];
            a0 += bf2f((unsigned short)(p0 & 0xffffu)) + bf2f((unsigned short)(p1 & 0xffffu))
                + bf2f((unsigned short)(p2 & 0xffffu)) + bf2f((unsigned short)(p3 & 0xffffu));
            a1 += bf2f((unsigned short)(p0 >> 16)) + bf2f((unsigned short)(p1 >> 16))
                + bf2f((unsigned short)(p2 >> 16)) + bf2f((unsigned short)(p3 >> 16));
        }
        for (; j < dcl; j++) {
            unsigned p = hbuf[(size_t)ep[j] * 64 + l];
            a0 += bf2f((unsigned short)(p & 0xffffu));
            a1 += bf2f((unsigned short)(p >> 16));
        }
        if (dv > CAP) {                     // scan tiny overflow list (novf ~ 0)
            int nv = *novf_ctr; nv = nv < OVFCAP ? nv : OVFCAP;
            for (int k = 0; k < nv; k++) {
                if (ovf[2 * k] == row) {
                    unsigned p = hbuf[(size_t)ovf[2 * k + 1] * 64 + l];
                    a0 += bf2f((unsigned short)(p & 0xffffu));
                    a1 += bf2f((unsigned short)(p >> 16));
                }
            }
        }
        smem_agg[lr][2 * l]     = a0;
        smem_agg[lr][2 * l + 1] = a1;
    }
    __syncthreads();

    // ---- Phase 2: stage z = [mean(128) || h(128)] into MFMA A-frag layout
    {
        const int r = t >> 4, seg = t & 15;
        const int row = row0 + r;
        const int c = seg >> 1;
        unsigned short tmp[16];
        if (seg < 8) {
            const int dv = deg[row];
            const float inv = (dv > 0) ? (1.f / (float)dv) : 0.f;
            const int k0 = seg * 16;
            #pragma unroll
            for (int i2 = 0; i2 < 16; i2++)
                tmp[i2] = f2bf(smem_agg[r][k0 + i2] * inv);
        } else {
            const unsigned short* hp =
                (const unsigned short*)hbuf + (size_t)row * 128 + (seg - 8) * 16;
            #pragma unroll
            for (int i2 = 0; i2 < 16; i2++) tmp[i2] = hp[i2];
        }
        #pragma unroll
        for (int half = 0; half < 2; half++) {
            const int q = ((seg & 1) << 1) + half;
            *(short8*)&a_lds[c][q * 16 + r][0] = *(short8*)&tmp[half * 8];
        }
    }
    __syncthreads();

    // ---- Phase 3: MFMA — wave computes 16 rows x 2 col-tiles
    short8 af[8];
    #pragma unroll
    for (int c = 0; c < 8; c++) af[c] = *(const short8*)&a_lds[c][l][0];

    float4v acc[2] = {{0.f,0.f,0.f,0.f},{0.f,0.f,0.f,0.f}};
    #pragma unroll
    for (int tt = 0; tt < 2; tt++) {
        const int tc = w * 2 + tt;
        const short8* bw = (const short8*)(wsb + (size_t)tc * 8 * 64 * 8);
        #pragma unroll
        for (int c = 0; c < 8; c++) {
            short8 bf = bw[c * 64 + l];
            acc[tt] = __builtin_amdgcn_mfma_f32_16x16x32_bf16(af[c], bf, acc[tt], 0, 0, 0);
        }
    }

    // ---- Phase 4: epilogue (+b_l +x), C/D layout: col=lane&15, row=quad*4+reg
    #pragma unroll
    for (int tt = 0; tt < 2; tt++) {
        const int col = (w * 2 + tt) * 16 + (l & 15);
        const float blv = bl[col];
        #pragma unroll
        for (int rr = 0; rr < 4; rr++) {
            const int row = row0 + (l >> 4) * 4 + rr;
            out[(size_t)row * 128 + col] = acc[tt][rr] + blv + x[(size_t)row * 128 + col];
        }
    }
}

extern "C" void kernel_launch(void* const* d_in, const int* in_sizes, int n_in,
                              void* d_out, int out_size, void* d_ws, size_t ws_size,
                              hipStream_t stream) {
    const float* x     = (const float*)d_in[0];
    const int*   ei    = (const int*)d_in[1];
    const float* gamma = (const float*)d_in[2];
    const float* beta  = (const float*)d_in[3];
    const float* Wl    = (const float*)d_in[4];
    const float* bl    = (const float*)d_in[5];
    const float* Wr    = (const float*)d_in[6];
    float* out = (float*)d_out;

    const int C = 128;
    const int N = in_sizes[0] / C;          // 100000
    const int E = in_sizes[1] / 2;          // 1600000

    char* ws = (char*)d_ws;
    size_t off = 0;
    unsigned* hbuf = (unsigned*)(ws + off);  off += (size_t)N * 256;           // 25.6 MB
    int* deg       = (int*)(ws + off);       off += (size_t)N * 4;             // 400 KB
    int* novf_ctr  = (int*)(ws + off);       off += 16;
    int* ovf       = (int*)(ws + off);       off += (size_t)OVFCAP * 8;        // 512 KB
    int* elist     = (int*)(ws + off);       off += (size_t)N * CAP * 4;       // 19.2 MB
    unsigned short* wsb = (unsigned short*)(ws + off);                         // 64 KB

    // zero deg + novf in one memset (contiguous)
    hipMemsetAsync(deg, 0, (size_t)N * 4 + 16, stream);

    const int EB  = (E / 4 + 255) / 256;    // 1563 edge blocks (4 edges/thread)
    const int LNB = (N + 3) / 4;            // 25000 LN blocks
    fused_pre_kernel<<<EB + LNB + 16, 256, 0, stream>>>(
        x, gamma, beta, hbuf, ei, deg, elist, novf_ctr, ovf, Wl, Wr, wsb,
        N, E, EB, LNB);
    fused_out_kernel<<<N / 16, 256, 0, stream>>>(
        out, deg, hbuf, x, wsb, bl, elist, novf_ctr, ovf);
}

// Round 4
// 300.637 us; speedup vs baseline: 1.2379x; 1.2379x over previous
//
#include <hip/hip_runtime.h>
#include <hip/hip_bf16.h>

typedef __attribute__((ext_vector_type(8))) short short8;
typedef __attribute__((ext_vector_type(4))) float float4v;

#define BN     128      // nodes per bucket (power of 2)
#define CHUNKS 256      // edge chunks for counting sort
#define ELCAP  3072     // LDS edge-list slots per bucket; E[cnt]=2048, +22 sigma
#define NBPAD  784

__device__ __forceinline__ unsigned short f2bf(float f) {
    union { float f; unsigned u; } v; v.f = f;
    unsigned r = v.u + 0x7fffu + ((v.u >> 16) & 1u);   // round-to-nearest-even
    return (unsigned short)(r >> 16);
}
__device__ __forceinline__ float bf2f(unsigned short u) {
    union { unsigned u; float f; } v; v.u = ((unsigned)u) << 16; return v.f;
}

// ---------------- K1: LayerNorm + ReLU -> packed bf16 h ----------------
__global__ __launch_bounds__(256) void ln_relu_kernel(
    const float* __restrict__ x, const float* __restrict__ gamma,
    const float* __restrict__ beta, unsigned* __restrict__ hbuf, int N) {
    const int row = blockIdx.x * 4 + (threadIdx.x >> 6);
    if (row >= N) return;
    const int lane = threadIdx.x & 63;
    const size_t base = (size_t)row * 128 + lane * 2;
    float2 v = *(const float2*)&x[base];
    float s = v.x + v.y;
    #pragma unroll
    for (int o = 32; o; o >>= 1) s += __shfl_xor(s, o, 64);
    const float mu = s * 0.0078125f;
    const float d0 = v.x - mu, d1 = v.y - mu;
    float ss = d0 * d0 + d1 * d1;
    #pragma unroll
    for (int o = 32; o; o >>= 1) ss += __shfl_xor(ss, o, 64);
    const float rs = rsqrtf(ss * 0.0078125f + 1e-5f);
    float2 g = *(const float2*)&gamma[lane * 2];
    float2 b = *(const float2*)&beta[lane * 2];
    float h0 = fmaxf(fmaf(d0 * rs, g.x, b.x), 0.f);
    float h1 = fmaxf(fmaf(d1 * rs, g.y, b.y), 0.f);
    hbuf[(size_t)row * 64 + lane] = (unsigned)f2bf(h0) | ((unsigned)f2bf(h1) << 16);
}

// ---------------- K2: pack W fragments (bf16, MFMA B-operand layout) ----
__global__ __launch_bounds__(256) void wprep_kernel(
    const float* __restrict__ Wl, const float* __restrict__ Wr,
    unsigned short* __restrict__ wsb) {
    const int s = blockIdx.x * 256 + threadIdx.x;       // 0..4095
    const int t = s >> 9, c = (s >> 6) & 7, l = s & 63;
    const int n  = t * 16 + (l & 15);
    const int k0 = c * 32 + ((l >> 4) & 3) * 8;
    const float* w = (k0 < 128) ? (Wl + (size_t)n * 128 + k0)
                                : (Wr + (size_t)n * 128 + (k0 - 128));
    unsigned short tmp[8];
    #pragma unroll
    for (int j = 0; j < 8; j++) tmp[j] = f2bf(w[j]);
    *(short8*)&wsb[(size_t)s * 8] = *(short8*)tmp;
}

// ---------------- K3: per-chunk bucket histogram (LDS atomics only) -----
__global__ __launch_bounds__(256) void count_kernel(
    const int* __restrict__ idx, int* __restrict__ counts, int E, int NB) {
    __shared__ int hist[NBPAD];
    const int t = threadIdx.x, c = blockIdx.x;
    for (int i = t; i < NB; i += 256) hist[i] = 0;
    __syncthreads();
    const int CH = (E + CHUNKS - 1) / CHUNKS;
    const int e0 = c * CH, e1 = min(E, e0 + CH);
    for (int e = e0 + t; e < e1; e += 256)
        atomicAdd(&hist[idx[E + e] >> 7], 1);
    __syncthreads();
    for (int i = t; i < NB; i += 256) counts[c * NBPAD + i] = hist[i];
}

// ---------------- K4: per-bucket exclusive prefix over chunks -----------
__global__ __launch_bounds__(256) void bscan_kernel(
    int* __restrict__ counts, int* __restrict__ totals, int NB) {
    const int b = blockIdx.x * 256 + threadIdx.x;
    if (b >= NB) return;
    int run = 0;
    for (int c = 0; c < CHUNKS; c++) {
        int u = counts[c * NBPAD + b];
        counts[c * NBPAD + b] = run;
        run += u;
    }
    totals[b] = run;
}

// ---------------- K5: scan bucket totals -> bucket start offsets --------
__global__ __launch_bounds__(1024) void tscan_kernel(
    const int* __restrict__ totals, int* __restrict__ bstart, int NB) {
    __shared__ int sd[1024];
    const int t = threadIdx.x;
    const int v = (t < NB) ? totals[t] : 0;
    sd[t] = v;
    __syncthreads();
    for (int off = 1; off < 1024; off <<= 1) {
        int u = (t >= off) ? sd[t - off] : 0;
        __syncthreads();
        sd[t] += u;
        __syncthreads();
    }
    if (t <= NB) bstart[t] = sd[t] - v;     // exclusive; bstart[NB] == E
}

// ---------------- K6: place (dst,src) pairs into dst-bucketed ebuf ------
__global__ __launch_bounds__(256) void bucket_kernel(
    const int* __restrict__ idx, const int* __restrict__ counts,
    const int* __restrict__ bstart, int2* __restrict__ ebuf, int E, int NB) {
    __shared__ int cur[NBPAD];
    const int t = threadIdx.x, c = blockIdx.x;
    for (int i = t; i < NB; i += 256) cur[i] = bstart[i] + counts[c * NBPAD + i];
    __syncthreads();
    const int CH = (E + CHUNKS - 1) / CHUNKS;
    const int e0 = c * CH, e1 = min(E, e0 + CH);
    for (int e = e0 + t; e < e1; e += 256) {
        const int src = idx[e];
        const int dst = idx[E + e];
        const int pos = atomicAdd(&cur[dst >> 7], 1);
        ebuf[pos] = make_int2(dst, src);
    }
}

// ---------------- K7: per-bucket adjacency (LDS) + gather + MFMA --------
// out[i][:] = mean_j h[j] @ W_l^T + b_l + h[i] @ W_r^T + x[i]
__global__ __launch_bounds__(256) void fused_out_kernel(
    float* __restrict__ out, const unsigned* __restrict__ hbuf,
    const float* __restrict__ x, const unsigned short* __restrict__ wsb,
    const float* __restrict__ bl, const int2* __restrict__ ebuf,
    const int* __restrict__ bstart, int N) {
    __shared__ int elds[ELCAP];                 // 12 KB
    __shared__ float smem_agg[16][128];         // 8 KB
    __shared__ unsigned short a_lds[8][64][8];  // 8 KB
    __shared__ int hist[BN], segstart[BN], cur2[BN];
    const int t = threadIdx.x, w = t >> 6, l = t & 63;
    const int b = blockIdx.x;
    const int nodebase = b * BN;
    const int e0 = bstart[b], cnt = bstart[b + 1] - e0;

    // ---- local per-node degree histogram
    if (t < BN) hist[t] = 0;
    __syncthreads();
    for (int i = t; i < cnt; i += 256) {
        int2 p = ebuf[e0 + i];
        atomicAdd(&hist[p.x & (BN - 1)], 1);
    }
    __syncthreads();
    // ---- exclusive scan of 128 degree counters
    if (t < BN) cur2[t] = hist[t];
    __syncthreads();
    for (int off = 1; off < BN; off <<= 1) {
        int u = (t < BN && t >= off) ? cur2[t - off] : 0;
        __syncthreads();
        if (t < BN) cur2[t] += u;
        __syncthreads();
    }
    if (t < BN) { segstart[t] = cur2[t] - hist[t]; cur2[t] = segstart[t]; }
    __syncthreads();
    // ---- place srcs into LDS edge list grouped by local dst
    for (int i = t; i < cnt; i += 256) {
        int2 p = ebuf[e0 + i];
        int pos = atomicAdd(&cur2[p.x & (BN - 1)], 1);
        if (pos < ELCAP) elds[pos] = p.y;
    }
    __syncthreads();

    // ---- 8 tiles of 16 rows: gather-reduce -> pack -> MFMA -> epilogue
    for (int tile = 0; tile < 8; tile++) {
        // P1: wave w gathers rows w*4..w*4+3 of this tile
        #pragma unroll
        for (int i = 0; i < 4; i++) {
            const int lr = w * 4 + i;
            const int ln = tile * 16 + lr;
            const int sp = segstart[ln];
            int dend = sp + hist[ln];
            if (dend > ELCAP) dend = ELCAP;
            float a0 = 0.f, a1 = 0.f;
            int j = sp;
            for (; j + 4 <= dend; j += 4) {
                int s0 = elds[j], s1 = elds[j + 1], s2 = elds[j + 2], s3 = elds[j + 3];
                unsigned p0 = hbuf[(size_t)s0 * 64 + l];
                unsigned p1 = hbuf[(size_t)s1 * 64 + l];
                unsigned p2 = hbuf[(size_t)s2 * 64 + l];
                unsigned p3 = hbuf[(size_t)s3 * 64 + l];
                a0 += bf2f((unsigned short)(p0 & 0xffffu)) + bf2f((unsigned short)(p1 & 0xffffu))
                    + bf2f((unsigned short)(p2 & 0xffffu)) + bf2f((unsigned short)(p3 & 0xffffu));
                a1 += bf2f((unsigned short)(p0 >> 16)) + bf2f((unsigned short)(p1 >> 16))
                    + bf2f((unsigned short)(p2 >> 16)) + bf2f((unsigned short)(p3 >> 16));
            }
            for (; j < dend; j++) {
                unsigned p = hbuf[(size_t)elds[j] * 64 + l];
                a0 += bf2f((unsigned short)(p & 0xffffu));
                a1 += bf2f((unsigned short)(p >> 16));
            }
            smem_agg[lr][2 * l]     = a0;
            smem_agg[lr][2 * l + 1] = a1;
        }
        __syncthreads();

        // P2: stage z = [mean(128) || h(128)] into MFMA A-frag layout
        {
            const int r = t >> 4, seg = t & 15;
            const int ln = tile * 16 + r;
            const int c8 = seg >> 1;
            unsigned short tmp[16];
            if (seg < 8) {
                const int dv = hist[ln];
                const float inv = (dv > 0) ? (1.f / (float)dv) : 0.f;
                const int k0 = seg * 16;
                #pragma unroll
                for (int i2 = 0; i2 < 16; i2++)
                    tmp[i2] = f2bf(smem_agg[r][k0 + i2] * inv);
            } else {
                const unsigned short* hp =
                    (const unsigned short*)hbuf + (size_t)(nodebase + ln) * 128 + (seg - 8) * 16;
                #pragma unroll
                for (int i2 = 0; i2 < 16; i2++) tmp[i2] = hp[i2];
            }
            #pragma unroll
            for (int half = 0; half < 2; half++) {
                const int q = ((seg & 1) << 1) + half;
                *(short8*)&a_lds[c8][q * 16 + r][0] = *(short8*)&tmp[half * 8];
            }
        }
        __syncthreads();

        // P3: MFMA — wave computes 16 rows x 2 col-tiles
        short8 af[8];
        #pragma unroll
        for (int c = 0; c < 8; c++) af[c] = *(const short8*)&a_lds[c][l][0];

        float4v acc[2] = {{0.f,0.f,0.f,0.f},{0.f,0.f,0.f,0.f}};
        #pragma unroll
        for (int tt = 0; tt < 2; tt++) {
            const int tc = w * 2 + tt;
            const short8* bw = (const short8*)(wsb + (size_t)tc * 8 * 64 * 8);
            #pragma unroll
            for (int c = 0; c < 8; c++) {
                short8 bf = bw[c * 64 + l];
                acc[tt] = __builtin_amdgcn_mfma_f32_16x16x32_bf16(af[c], bf, acc[tt], 0, 0, 0);
            }
        }

        // epilogue (+b_l +x); C/D layout: col=lane&15, row=quad*4+reg
        #pragma unroll
        for (int tt = 0; tt < 2; tt++) {
            const int col = (w * 2 + tt) * 16 + (l & 15);
            const float blv = bl[col];
            #pragma unroll
            for (int rr = 0; rr < 4; rr++) {
                const int row = nodebase + tile * 16 + (l >> 4) * 4 + rr;
                if (row < N)
                    out[(size_t)row * 128 + col] = acc[tt][rr] + blv + x[(size_t)row * 128 + col];
            }
        }
        __syncthreads();
    }
}

extern "C" void kernel_launch(void* const* d_in, const int* in_sizes, int n_in,
                              void* d_out, int out_size, void* d_ws, size_t ws_size,
                              hipStream_t stream) {
    const float* x     = (const float*)d_in[0];
    const int*   ei    = (const int*)d_in[1];
    const float* gamma = (const float*)d_in[2];
    const float* beta  = (const float*)d_in[3];
    const float* Wl    = (const float*)d_in[4];
    const float* bl    = (const float*)d_in[5];
    const float* Wr    = (const float*)d_in[6];
    float* out = (float*)d_out;

    const int C = 128;
    const int N = in_sizes[0] / C;          // 100000
    const int E = in_sizes[1] / 2;          // 1600000
    const int NB = (N + BN - 1) / BN;       // 782

    char* ws = (char*)d_ws;
    size_t off = 0;
    unsigned* hbuf = (unsigned*)(ws + off);  off += (size_t)N * 256;            // 25.6 MB
    int2* ebuf     = (int2*)(ws + off);      off += (size_t)E * 8;              // 12.8 MB
    int* counts    = (int*)(ws + off);       off += (size_t)CHUNKS * NBPAD * 4; // 803 KB
    int* totals    = (int*)(ws + off);       off += 4096;
    int* bstart    = (int*)(ws + off);       off += 4096;
    unsigned short* wsb = (unsigned short*)(ws + off);                          // 64 KB

    ln_relu_kernel<<<(N + 3) / 4, 256, 0, stream>>>(x, gamma, beta, hbuf, N);
    wprep_kernel<<<16, 256, 0, stream>>>(Wl, Wr, wsb);
    count_kernel<<<CHUNKS, 256, 0, stream>>>(ei, counts, E, NB);
    bscan_kernel<<<(NB + 255) / 256, 256, 0, stream>>>(counts, totals, NB);
    tscan_kernel<<<1, 1024, 0, stream>>>(totals, bstart, NB);
    bucket_kernel<<<CHUNKS, 256, 0, stream>>>(ei, counts, bstart, ebuf, E, NB);
    fused_out_kernel<<<NB, 256, 0, stream>>>(out, hbuf, x, wsb, bl, ebuf, bstart, N);
}

// Round 5
// 292.847 us; speedup vs baseline: 1.2708x; 1.0266x over previous
//
#include <hip/hip_runtime.h>
#include <hip/hip_bf16.h>

typedef __attribute__((ext_vector_type(8))) short short8;
typedef __attribute__((ext_vector_type(4))) float float4v;

#define BN     64       // nodes per bucket
#define CHUNKS 128      // edge chunks for counting sort
#define ELCAP  1536     // LDS edge slots per bucket; mean 1024, +16 sigma
#define NBPAD  1568     // padded bucket count (NB=1563)
#define SAP    136      // smem_agg row pad (words): breaks P2 read conflicts

__device__ __forceinline__ unsigned short f2bf(float f) {
    union { float f; unsigned u; } v; v.f = f;
    unsigned r = v.u + 0x7fffu + ((v.u >> 16) & 1u);   // round-to-nearest-even
    return (unsigned short)(r >> 16);
}
__device__ __forceinline__ float bf2f(unsigned short u) {
    union { unsigned u; float f; } v; v.u = ((unsigned)u) << 16; return v.f;
}

// ---------------- K1: fused [count | LN+ReLU | W-prep] ------------------
// b < CHUNKS:              per-chunk bucket histogram (LDS atomics, coalesced out)
// CHUNKS <= b < CHUNKS+LNB: LayerNorm+ReLU -> packed bf16 h (wave per row)
// else (16 blocks):        pack W fragments (MFMA B layout)
__global__ __launch_bounds__(256) void fused_pre_kernel(
    const float* __restrict__ x, const float* __restrict__ gamma,
    const float* __restrict__ beta, unsigned* __restrict__ hbuf,
    const int* __restrict__ idx, int* __restrict__ counts,
    const float* __restrict__ Wl, const float* __restrict__ Wr,
    unsigned short* __restrict__ wsb, int N, int E, int NB, int LNB) {
    const int b = blockIdx.x, t = threadIdx.x;
    if (b < CHUNKS) {
        __shared__ int hist[NBPAD];
        for (int i = t; i < NB; i += 256) hist[i] = 0;
        __syncthreads();
        const int CH = (E + CHUNKS - 1) / CHUNKS;
        const int e0 = b * CH, e1 = min(E, e0 + CH);
        for (int e = e0 + t; e < e1; e += 256)
            atomicAdd(&hist[idx[E + e] >> 6], 1);
        __syncthreads();
        for (int i = t; i < NB; i += 256) counts[b * NBPAD + i] = hist[i];
    } else if (b < CHUNKS + LNB) {
        const int row = (b - CHUNKS) * 4 + (t >> 6);
        if (row >= N) return;
        const int lane = t & 63;
        const size_t base = (size_t)row * 128 + lane * 2;
        float2 v = *(const float2*)&x[base];
        float s = v.x + v.y;
        #pragma unroll
        for (int o = 32; o; o >>= 1) s += __shfl_xor(s, o, 64);
        const float mu = s * 0.0078125f;
        const float d0 = v.x - mu, d1 = v.y - mu;
        float ss = d0 * d0 + d1 * d1;
        #pragma unroll
        for (int o = 32; o; o >>= 1) ss += __shfl_xor(ss, o, 64);
        const float rs = rsqrtf(ss * 0.0078125f + 1e-5f);
        float2 g = *(const float2*)&gamma[lane * 2];
        float2 bb = *(const float2*)&beta[lane * 2];
        float h0 = fmaxf(fmaf(d0 * rs, g.x, bb.x), 0.f);
        float h1 = fmaxf(fmaf(d1 * rs, g.y, bb.y), 0.f);
        hbuf[(size_t)row * 64 + lane] = (unsigned)f2bf(h0) | ((unsigned)f2bf(h1) << 16);
    } else {
        const int s = (b - CHUNKS - LNB) * 256 + t;     // 0..4095
        const int tc = s >> 9, c = (s >> 6) & 7, l = s & 63;
        const int n  = tc * 16 + (l & 15);
        const int k0 = c * 32 + ((l >> 4) & 3) * 8;
        const float* w = (k0 < 128) ? (Wl + (size_t)n * 128 + k0)
                                    : (Wr + (size_t)n * 128 + (k0 - 128));
        unsigned short tmp[8];
        #pragma unroll
        for (int j = 0; j < 8; j++) tmp[j] = f2bf(w[j]);
        *(short8*)&wsb[(size_t)s * 8] = *(short8*)tmp;
    }
}

// ---------------- K2: per-bucket exclusive prefix over chunks (1 wave/bucket)
__global__ __launch_bounds__(256) void bscan_kernel(
    int* __restrict__ counts, int* __restrict__ totals, int NB) {
    const int b = blockIdx.x * 4 + (threadIdx.x >> 6);
    if (b >= NB) return;
    const int lane = threadIdx.x & 63;
    const int c0 = 2 * lane, c1 = 2 * lane + 1;
    const int u0 = counts[c0 * NBPAD + b];
    const int u1 = counts[c1 * NBPAD + b];
    int s = u0 + u1;
    #pragma unroll
    for (int o = 1; o < 64; o <<= 1) {
        int v = __shfl_up(s, o, 64);
        if (lane >= o) s += v;
    }
    const int excl = s - (u0 + u1);
    counts[c0 * NBPAD + b] = excl;
    counts[c1 * NBPAD + b] = excl + u0;
    if (lane == 63) totals[b] = s;
}

// ---------------- K3: scan bucket totals -> bstart (2 vals/thread) ------
__global__ __launch_bounds__(1024) void tscan_kernel(
    const int* __restrict__ totals, int* __restrict__ bstart, int NB) {
    __shared__ int sd[1024];
    const int t = threadIdx.x;
    const int i0 = 2 * t, i1 = 2 * t + 1;
    const int v0 = (i0 < NB) ? totals[i0] : 0;
    const int v1 = (i1 < NB) ? totals[i1] : 0;
    const int pr = v0 + v1;
    sd[t] = pr;
    __syncthreads();
    for (int off = 1; off < 1024; off <<= 1) {
        int u = (t >= off) ? sd[t - off] : 0;
        __syncthreads();
        sd[t] += u;
        __syncthreads();
    }
    const int ex = sd[t] - pr;
    if (i0 <= NB) bstart[i0] = ex;
    if (i1 <= NB) bstart[i1] = ex + v0;
}

// ---------------- K4: place (dst,src) pairs into dst-bucketed ebuf ------
__global__ __launch_bounds__(256) void bucket_kernel(
    const int* __restrict__ idx, const int* __restrict__ counts,
    const int* __restrict__ bstart, int2* __restrict__ ebuf, int E, int NB) {
    __shared__ int cur[NBPAD];
    const int t = threadIdx.x, c = blockIdx.x;
    for (int i = t; i < NB; i += 256) cur[i] = bstart[i] + counts[c * NBPAD + i];
    __syncthreads();
    const int CH = (E + CHUNKS - 1) / CHUNKS;
    const int e0 = c * CH, e1 = min(E, e0 + CH);
    for (int e = e0 + t; e < e1; e += 256) {
        const int src = idx[e];
        const int dst = idx[E + e];
        const int pos = atomicAdd(&cur[dst >> 6], 1);
        ebuf[pos] = make_int2(dst, src);
    }
}

// ---------------- K5: per-bucket adjacency (LDS) + gather + MFMA --------
// out[i][:] = mean_j h[j] @ W_l^T + b_l + h[i] @ W_r^T + x[i]
__global__ __launch_bounds__(256) void fused_out_kernel(
    float* __restrict__ out, const unsigned* __restrict__ hbuf,
    const float* __restrict__ x, const unsigned short* __restrict__ wsb,
    const float* __restrict__ bl, const int2* __restrict__ ebuf,
    const int* __restrict__ bstart, int N) {
    __shared__ int elds[ELCAP];                 // 6 KB
    __shared__ float smem_agg[16][SAP];         // 8.7 KB (padded rows)
    __shared__ unsigned short a_lds[8][64][8];  // 8 KB
    __shared__ int hist[BN], segstart[BN], cur2[BN];
    const int t = threadIdx.x, w = t >> 6, l = t & 63;
    const int b = blockIdx.x;
    const int nodebase = b * BN;
    const int e0 = bstart[b], cnt = bstart[b + 1] - e0;

    // ---- local per-node degree histogram
    if (t < BN) hist[t] = 0;
    __syncthreads();
    for (int i = t; i < cnt; i += 256) {
        int2 p = ebuf[e0 + i];
        atomicAdd(&hist[p.x & (BN - 1)], 1);
    }
    __syncthreads();
    if (t < BN) cur2[t] = hist[t];
    __syncthreads();
    for (int off = 1; off < BN; off <<= 1) {
        int u = (t < BN && t >= off) ? cur2[t - off] : 0;
        __syncthreads();
        if (t < BN) cur2[t] += u;
        __syncthreads();
    }
    if (t < BN) { segstart[t] = cur2[t] - hist[t]; cur2[t] = segstart[t]; }
    __syncthreads();
    for (int i = t; i < cnt; i += 256) {
        int2 p = ebuf[e0 + i];
        int pos = atomicAdd(&cur2[p.x & (BN - 1)], 1);
        if (pos < ELCAP) elds[pos] = p.y;
    }
    __syncthreads();

    // ---- 4 tiles of 16 rows
    for (int tile = 0; tile < 4; tile++) {
        // P1: wave w gathers rows w*4..w*4+3 (8-deep load ILP)
        #pragma unroll
        for (int i = 0; i < 4; i++) {
            const int lr = w * 4 + i;
            const int ln = tile * 16 + lr;
            const int sp = segstart[ln];
            int dend = sp + hist[ln];
            if (dend > ELCAP) dend = ELCAP;
            float a0 = 0.f, a1 = 0.f;
            int j = sp;
            for (; j + 8 <= dend; j += 8) {
                unsigned p[8];
                #pragma unroll
                for (int k = 0; k < 8; k++)
                    p[k] = hbuf[(size_t)elds[j + k] * 64 + l];
                #pragma unroll
                for (int k = 0; k < 8; k++) {
                    a0 += bf2f((unsigned short)(p[k] & 0xffffu));
                    a1 += bf2f((unsigned short)(p[k] >> 16));
                }
            }
            for (; j < dend; j++) {
                unsigned p = hbuf[(size_t)elds[j] * 64 + l];
                a0 += bf2f((unsigned short)(p & 0xffffu));
                a1 += bf2f((unsigned short)(p >> 16));
            }
            *(float2*)&smem_agg[lr][2 * l] = make_float2(a0, a1);
        }
        __syncthreads();

        // P2: stage z = [mean(128) || h(128)] into MFMA A-frag layout
        {
            const int r = t >> 4, seg = t & 15;
            const int ln = tile * 16 + r;
            const int c8 = seg >> 1;
            unsigned short tmp[16];
            if (seg < 8) {
                const int dv = hist[ln];
                const float inv = (dv > 0) ? (1.f / (float)dv) : 0.f;
                const float4v* sp4 = (const float4v*)&smem_agg[r][seg * 16];
                #pragma unroll
                for (int q4 = 0; q4 < 4; q4++) {
                    float4v v = sp4[q4];
                    tmp[q4*4+0] = f2bf(v.x * inv); tmp[q4*4+1] = f2bf(v.y * inv);
                    tmp[q4*4+2] = f2bf(v.z * inv); tmp[q4*4+3] = f2bf(v.w * inv);
                }
            } else {
                const unsigned short* hp =
                    (const unsigned short*)hbuf + (size_t)(nodebase + ln) * 128 + (seg - 8) * 16;
                #pragma unroll
                for (int i2 = 0; i2 < 16; i2++) tmp[i2] = hp[i2];
            }
            #pragma unroll
            for (int half = 0; half < 2; half++) {
                const int q = ((seg & 1) << 1) + half;
                *(short8*)&a_lds[c8][q * 16 + r][0] = *(short8*)&tmp[half * 8];
            }
        }
        __syncthreads();

        // P3: MFMA — wave computes 16 rows x 2 col-tiles
        short8 af[8];
        #pragma unroll
        for (int c = 0; c < 8; c++) af[c] = *(const short8*)&a_lds[c][l][0];

        float4v acc[2] = {{0.f,0.f,0.f,0.f},{0.f,0.f,0.f,0.f}};
        #pragma unroll
        for (int tt = 0; tt < 2; tt++) {
            const int tc = w * 2 + tt;
            const short8* bw = (const short8*)(wsb + (size_t)tc * 8 * 64 * 8);
            #pragma unroll
            for (int c = 0; c < 8; c++) {
                short8 bf = bw[c * 64 + l];
                acc[tt] = __builtin_amdgcn_mfma_f32_16x16x32_bf16(af[c], bf, acc[tt], 0, 0, 0);
            }
        }

        // epilogue (+b_l +x); C/D layout: col=lane&15, row=quad*4+reg
        #pragma unroll
        for (int tt = 0; tt < 2; tt++) {
            const int col = (w * 2 + tt) * 16 + (l & 15);
            const float blv = bl[col];
            #pragma unroll
            for (int rr = 0; rr < 4; rr++) {
                const int row = nodebase + tile * 16 + (l >> 4) * 4 + rr;
                if (row < N)
                    out[(size_t)row * 128 + col] = acc[tt][rr] + blv + x[(size_t)row * 128 + col];
            }
        }
        __syncthreads();
    }
}

extern "C" void kernel_launch(void* const* d_in, const int* in_sizes, int n_in,
                              void* d_out, int out_size, void* d_ws, size_t ws_size,
                              hipStream_t stream) {
    const float* x     = (const float*)d_in[0];
    const int*   ei    = (const int*)d_in[1];
    const float* gamma = (const float*)d_in[2];
    const float* beta  = (const float*)d_in[3];
    const float* Wl    = (const float*)d_in[4];
    const float* bl    = (const float*)d_in[5];
    const float* Wr    = (const float*)d_in[6];
    float* out = (float*)d_out;

    const int C = 128;
    const int N = in_sizes[0] / C;          // 100000
    const int E = in_sizes[1] / 2;          // 1600000
    const int NB = (N + BN - 1) / BN;       // 1563

    char* ws = (char*)d_ws;
    size_t off = 0;
    unsigned* hbuf = (unsigned*)(ws + off);  off += (size_t)N * 256;            // 25.6 MB
    int2* ebuf     = (int2*)(ws + off);      off += (size_t)E * 8;              // 12.8 MB
    int* counts    = (int*)(ws + off);       off += (size_t)CHUNKS * NBPAD * 4; // 803 KB
    int* totals    = (int*)(ws + off);       off += 8192;
    int* bstart    = (int*)(ws + off);       off += 8192;
    unsigned short* wsb = (unsigned short*)(ws + off);                          // 64 KB

    const int LNB = (N + 3) / 4;            // 25000
    fused_pre_kernel<<<CHUNKS + LNB + 16, 256, 0, stream>>>(
        x, gamma, beta, hbuf, ei, counts, Wl, Wr, wsb, N, E, NB, LNB);
    bscan_kernel<<<(NB + 3) / 4, 256, 0, stream>>>(counts, totals, NB);
    tscan_kernel<<<1, 1024, 0, stream>>>(totals, bstart, NB);
    bucket_kernel<<<CHUNKS, 256, 0, stream>>>(ei, counts, bstart, ebuf, E, NB);
    fused_out_kernel<<<NB, 256, 0, stream>>>(out, hbuf, x, wsb, bl, ebuf, bstart, N);
}